// Round 5
// baseline (119.362 us; speedup 1.0000x reference)
//
#include <hip/hip_runtime.h>
#include <math.h>

#define TEMP_F 0.07f
#define NCON 20
#define LDIM 512
#define NROWS 32768
#define NSEL 16384

// ws layout: [0 .. 32768) uint32 packed multiplicity counts:
//   low 16 bits  = # occurrences of row r in sz_idx
//   high 16 bits = # occurrences of row r in nsz_idx
// loss = (1/NSEL) * sum_r [ c_sz(r)*term_sz(r) + c_nsz(r)*term_nsz(r) ]
//   term_b(r) = log(den_b(r)) - dot(hg_r, ebar_b)/(T * max(||hg_r||,1e-12))

__global__ __launch_bounds__(256) void init_kernel(unsigned* __restrict__ cnt,
                                                   float* __restrict__ out) {
    // 32 blocks x 256 threads x uint4 = 32768 words
    ((uint4*)cnt)[blockIdx.x * 256 + threadIdx.x] = make_uint4(0u, 0u, 0u, 0u);
    if (blockIdx.x == 0 && threadIdx.x == 0) out[0] = 0.f;  // out poisoned each call
}

__global__ __launch_bounds__(256) void hist_kernel(const int* __restrict__ sz_idx,
                                                   const int* __restrict__ nsz_idx,
                                                   unsigned* __restrict__ cnt) {
    const int i = blockIdx.x * 256 + threadIdx.x;  // 128 blocks -> 32768 threads
    if (i < NSEL) atomicAdd(&cnt[sz_idx[i]], 1u);
    else          atomicAdd(&cnt[nsz_idx[i - NSEL]], 0x10000u);
}

__device__ inline float dot4(float4 a, float4 b) {
    return a.x * b.x + a.y * b.y + a.z * b.z + a.w * b.w;
}

// 1024 blocks x 512 threads (8 waves). Wave g owns 4 CONTIGUOUS rows
// [g*4, g*4+4): hg stream stays fully sequential, all loads issued
// unconditionally up front (R4 lesson: conditional per-row loads expose
// HBM latency serially). sim is read in the same row order (coalesced).
__global__ __launch_bounds__(512) void main_kernel(const float* __restrict__ hg,
                                                   const float* __restrict__ sim,
                                                   const float* __restrict__ all_emb,
                                                   const int* __restrict__ Psz,
                                                   const int* __restrict__ Pnsz,
                                                   const unsigned* __restrict__ cnt,
                                                   float* __restrict__ out) {
    __shared__ float ebs[LDIM];
    __shared__ float ebn[LDIM];
    __shared__ float red[8];
    const int t = threadIdx.x;

    // per-block e_bar build (all_emb 40 KB, L2-resident; duplicates in P
    // counted in the mean — matches ref's all_emb[P_idx].mean(0))
    for (int j = t; j < LDIM; j += 512) {
        float s1 = 0.f, s2 = 0.f;
#pragma unroll
        for (int k = 0; k < 5; ++k) {
            s1 += all_emb[Psz[k]  * LDIM + j];
            s2 += all_emb[Pnsz[k] * LDIM + j];
        }
        ebs[j] = s1 * 0.2f;
        ebn[j] = s2 * 0.2f;
    }
    // keep-masks (duplicate P entries idempotent — matches at[P].set(0))
    unsigned msz = (1u << NCON) - 1u, mnsz = (1u << NCON) - 1u;
#pragma unroll
    for (int k = 0; k < 5; ++k) { msz &= ~(1u << Psz[k]); mnsz &= ~(1u << Pnsz[k]); }
    __syncthreads();

    const int lane = t & 63;
    const int w    = t >> 6;

    const float4 es0 = ((const float4*)ebs)[lane * 2];
    const float4 es1 = ((const float4*)ebs)[lane * 2 + 1];
    const float4 en0 = ((const float4*)ebn)[lane * 2];
    const float4 en1 = ((const float4*)ebn)[lane * 2 + 1];

    const int wave = blockIdx.x * 8 + w;   // 0..8191
    const int row0 = wave * 4;

    // all loads up front, unconditional
    const uint4 c4 = ((const uint4*)cnt)[wave];
    const unsigned cc[4] = {c4.x, c4.y, c4.z, c4.w};

    const float4* hp = (const float4*)hg + (size_t)row0 * (LDIM / 4) + lane * 2;
    float4 A[4][2];
#pragma unroll
    for (int k = 0; k < 4; ++k) {
        A[k][0] = hp[(size_t)k * (LDIM / 4)];
        A[k][1] = hp[(size_t)k * (LDIM / 4) + 1];
    }
    float sv[4];
#pragma unroll
    for (int k = 0; k < 4; ++k)
        sv[k] = (lane < NCON) ? sim[(size_t)(row0 + k) * NCON + lane] : 0.f;

    const float invT = 1.0f / TEMP_F;
    const bool keep_s = (lane < NCON) && (msz  & (1u << (lane & 31)));
    const bool keep_n = (lane < NCON) && (mnsz & (1u << (lane & 31)));

    float acc = 0.f;
#pragma unroll
    for (int k = 0; k < 4; ++k) {
        const float wsz = (float)(cc[k] & 0xFFFFu);
        const float wnz = (float)(cc[k] >> 16);
        const float4 a0 = A[k][0], a1 = A[k][1];

        float ss = dot4(a0, a0)  + dot4(a1, a1);
        float ds = dot4(a0, es0) + dot4(a1, es1);
        float dn = dot4(a0, en0) + dot4(a1, en1);
        const float e = (lane < NCON) ? expf(sv[k] * invT) : 0.f;
        float des = keep_s ? e : 0.f;
        float den = keep_n ? e : 0.f;

#pragma unroll
        for (int off = 32; off; off >>= 1) {
            ss  += __shfl_xor(ss,  off);
            ds  += __shfl_xor(ds,  off);
            dn  += __shfl_xor(dn,  off);
            des += __shfl_xor(des, off);
            den += __shfl_xor(den, off);
        }
        acc += wsz * logf(des) + wnz * logf(den)
             - (wsz * ds + wnz * dn) * invT / fmaxf(sqrtf(ss), 1e-12f);
    }

    // block reduction (acc identical across the wave's lanes)
    if (lane == 0) red[w] = acc;
    __syncthreads();
    if (t == 0) {
        float bsum = 0.f;
#pragma unroll
        for (int j = 0; j < 8; ++j) bsum += red[j];
        atomicAdd(out, bsum * (1.0f / NSEL));
    }
}

extern "C" void kernel_launch(void* const* d_in, const int* in_sizes, int n_in,
                              void* d_out, int out_size, void* d_ws, size_t ws_size,
                              hipStream_t stream) {
    const float* hg       = (const float*)d_in[0];
    const float* hg_corr  = (const float*)d_in[1];
    const float* all_emb  = (const float*)d_in[2];
    const int*   sz_idx   = (const int*)d_in[3];
    const int*   nsz_idx  = (const int*)d_in[4];
    const int*   Psz      = (const int*)d_in[5];
    const int*   Pnsz     = (const int*)d_in[6];
    float* out = (float*)d_out;
    unsigned* cnt = (unsigned*)d_ws;

    init_kernel<<<32, 256, 0, stream>>>(cnt, out);
    hist_kernel<<<128, 256, 0, stream>>>(sz_idx, nsz_idx, cnt);
    main_kernel<<<1024, 512, 0, stream>>>(hg, hg_corr, all_emb, Psz, Pnsz, cnt, out);
}

// Round 6
// 110.226 us; speedup vs baseline: 1.0829x; 1.0829x over previous
//
#include <hip/hip_runtime.h>
#include <math.h>

#define TEMP_F 0.07f
#define NCON 20
#define LDIM 512
#define NROWS 32768
#define NSEL 16384

// ws layout: float4 stats[32768] (512 KB):
//   stats[r] = { ||hg_r||_2 , <hg_r, ebar_sz> , <hg_r, ebar_nsz> , unused }
// Interleaved so the branch pass does ONE 16B gather per selection.

__device__ inline float dot4(float4 a, float4 b) {
    return a.x * b.x + a.y * b.y + a.z * b.z + a.w * b.w;
}

// 1024 blocks x 256 threads = 4096 waves; wave g owns rows [8g, 8g+8),
// processed as two batches of 4 rows with ALL loads issued unconditionally
// up front (8 float4 in flight per lane) — R4 lesson: no conditional loads;
// R3 lesson: keep the hg stream sequential.
__global__ __launch_bounds__(256) void rowstats_kernel(const float* __restrict__ hg,
                                                       const float* __restrict__ all_emb,
                                                       const int* __restrict__ Psz,
                                                       const int* __restrict__ Pnsz,
                                                       float4* __restrict__ stats,
                                                       float* __restrict__ out) {
    __shared__ float ebs[LDIM];
    __shared__ float ebn[LDIM];
    const int t = threadIdx.x;

    // per-block e_bar build (all_emb 40 KB, L2-resident; 1024 rebuilds ~20 MB
    // of L2 traffic ~0.6 us). Duplicate P entries counted — matches ref mean.
    for (int j = t; j < LDIM; j += 256) {
        float s1 = 0.f, s2 = 0.f;
#pragma unroll
        for (int k = 0; k < 5; ++k) {
            s1 += all_emb[Psz[k]  * LDIM + j];
            s2 += all_emb[Pnsz[k] * LDIM + j];
        }
        ebs[j] = s1 * 0.2f;
        ebn[j] = s2 * 0.2f;
    }
    if (blockIdx.x == 0 && t == 0) out[0] = 0.f;   // d_out poisoned each call
    __syncthreads();

    const int lane = t & 63;
    const int w    = t >> 6;

    const float4 es0 = ((const float4*)ebs)[lane * 2];
    const float4 es1 = ((const float4*)ebs)[lane * 2 + 1];
    const float4 en0 = ((const float4*)ebn)[lane * 2];
    const float4 en1 = ((const float4*)ebn)[lane * 2 + 1];

    const int wave = blockIdx.x * 4 + w;   // 0..4095
    const int row0 = wave * 8;

#pragma unroll
    for (int half = 0; half < 2; ++half) {
        const int rb = row0 + half * 4;
        const float4* hp = (const float4*)hg + (size_t)rb * (LDIM / 4) + lane * 2;

        // 8 unconditional loads up front — deep MLP
        float4 A[4][2];
#pragma unroll
        for (int k = 0; k < 4; ++k) {
            A[k][0] = hp[(size_t)k * (LDIM / 4)];
            A[k][1] = hp[(size_t)k * (LDIM / 4) + 1];
        }

#pragma unroll
        for (int k = 0; k < 4; ++k) {
            const float4 a0 = A[k][0], a1 = A[k][1];
            float ss = dot4(a0, a0)  + dot4(a1, a1);
            float ds = dot4(a0, es0) + dot4(a1, es1);
            float dn = dot4(a0, en0) + dot4(a1, en1);
#pragma unroll
            for (int off = 32; off; off >>= 1) {
                ss += __shfl_xor(ss, off);
                ds += __shfl_xor(ds, off);
                dn += __shfl_xor(dn, off);
            }
            if (lane == 0)
                stats[rb + k] = make_float4(sqrtf(ss), ds, dn, 0.f);
        }
    }
}

// gridDim = (64, 2): 16384 threads per branch, branch = blockIdx.y
__global__ __launch_bounds__(256) void branch_kernel(const float* __restrict__ sim,
                                                     const int* __restrict__ sz_idx,
                                                     const int* __restrict__ nsz_idx,
                                                     const int* __restrict__ Psz,
                                                     const int* __restrict__ Pnsz,
                                                     const float4* __restrict__ stats,
                                                     float* __restrict__ out) {
    const int b = blockIdx.y;
    const int* __restrict__ idx = (b == 0) ? sz_idx : nsz_idx;
    const int* __restrict__ P   = (b == 0) ? Psz : Pnsz;

    unsigned mask = (1u << NCON) - 1u;
#pragma unroll
    for (int k = 0; k < 5; ++k) mask &= ~(1u << P[k]);

    const int i = blockIdx.x * blockDim.x + threadIdx.x;  // < 16384 exactly
    const int r = idx[i];

    // one 16B stat gather + 80B sim row (5 x float4), all issued up front
    const float4 st = stats[r];
    const float4* srow = (const float4*)(sim + (size_t)r * NCON);
    float4 v0 = srow[0], v1 = srow[1], v2 = srow[2], v3 = srow[3], v4 = srow[4];
    float s[NCON] = {v0.x, v0.y, v0.z, v0.w, v1.x, v1.y, v1.z, v1.w,
                     v2.x, v2.y, v2.z, v2.w, v3.x, v3.y, v3.z, v3.w,
                     v4.x, v4.y, v4.z, v4.w};

    const float invT = 1.0f / TEMP_F;
    float den = 0.f;
#pragma unroll
    for (int j = 0; j < NCON; ++j)
        if (mask & (1u << j)) den += expf(s[j] * invT);

    const float dot = (b == 0) ? st.y : st.z;
    float term = logf(den) - dot * invT / fmaxf(st.x, 1e-12f);

    __shared__ float red[4];
#pragma unroll
    for (int off = 32; off; off >>= 1) term += __shfl_xor(term, off);
    const int lane = threadIdx.x & 63;
    const int w = threadIdx.x >> 6;
    if (lane == 0) red[w] = term;
    __syncthreads();
    if (threadIdx.x == 0) {
        float bsum = red[0] + red[1] + red[2] + red[3];
        atomicAdd(out, bsum * (1.0f / NSEL));
    }
}

extern "C" void kernel_launch(void* const* d_in, const int* in_sizes, int n_in,
                              void* d_out, int out_size, void* d_ws, size_t ws_size,
                              hipStream_t stream) {
    const float* hg       = (const float*)d_in[0];
    const float* hg_corr  = (const float*)d_in[1];
    const float* all_emb  = (const float*)d_in[2];
    const int*   sz_idx   = (const int*)d_in[3];
    const int*   nsz_idx  = (const int*)d_in[4];
    const int*   Psz      = (const int*)d_in[5];
    const int*   Pnsz     = (const int*)d_in[6];
    float* out = (float*)d_out;
    float4* stats = (float4*)d_ws;

    rowstats_kernel<<<1024, 256, 0, stream>>>(hg, all_emb, Psz, Pnsz, stats, out);
    dim3 g(64, 2);
    branch_kernel<<<g, 256, 0, stream>>>(hg_corr, sz_idx, nsz_idx, Psz, Pnsz, stats, out);
}